// Round 8
// baseline (418.944 us; speedup 1.0000x reference)
//
#include <hip/hip_runtime.h>
#include <hip/hip_bf16.h>

#define N_USERS 100000
#define N_ITEMS 50000
#define N_TOT   150000
#define D       64
#define NBUCK   ((N_ITEMS + 127) >> 7)   // 391 coarse buckets of 128 items
#define BCAP    6144                     // bucket capacity

typedef float v2f __attribute__((ext_vector_type(2)));

// ---------------- helpers ----------------
__device__ __forceinline__ unsigned bf16rn(float f) {        // fp32 -> bf16 bits (RNE)
    unsigned x = __float_as_uint(f);
    return (x + 0x7FFFu + ((x >> 16) & 1u)) >> 16;
}
__device__ __forceinline__ unsigned packbf(float a, float b) {
    return bf16rn(a) | (bf16rn(b) << 16);
}

// ---------------- preprocessing ----------------

#define BS_B 391    // ceil(100001/256)
__global__ __launch_bounds__(256) void pre_misc_kernel(
        const int* __restrict__ rows, int* __restrict__ user_ptr, int E,
        const int* __restrict__ users, const int* __restrict__ pos,
        const int* __restrict__ neg, unsigned char* __restrict__ flags, int B) {
    int b = blockIdx.x, t = threadIdx.x;
    if (b < BS_B) {
        int r = b * 256 + t;
        if (r <= N_USERS) {
            int lo = 0, hi = E;
            while (lo < hi) {
                int mid = (lo + hi) >> 1;
                if (rows[mid] < r) lo = mid + 1; else hi = mid;
            }
            user_ptr[r] = lo;
        }
    } else {
        int k = (b - BS_B) * 256 + t;
        if (k < 3 * B) {
            int row;
            if (k < B)          row = users[k];
            else if (k < 2 * B) row = N_USERS + pos[k - B];
            else                row = N_USERS + neg[k - 2 * B];
            flags[row] = 1;
        }
    }
}

// Coarse scatter into fixed-capacity buckets. Payload: ((i&127)<<17)|u (int).
__global__ __launch_bounds__(256) void coarse_scatter_kernel(
        const int* __restrict__ rows, const int* __restrict__ cols,
        int* __restrict__ ccur, int* __restrict__ tmp,
        unsigned short* __restrict__ cols16, int E) {
    __shared__ int cnt[NBUCK];
    __shared__ int basep[NBUCK];
    const int K = 16;
    int chunk = blockIdx.x * (256 * K);
    for (int i = threadIdx.x; i < NBUCK; i += 256) cnt[i] = 0;
    __syncthreads();
    int pk[K]; int bk[K];
    #pragma unroll
    for (int k = 0; k < K; ++k) {
        int e = chunk + k * 256 + (int)threadIdx.x;
        if (e < E) {
            int i = cols[e] - N_USERS;
            cols16[e] = (unsigned short)i;
            bk[k] = i >> 7;
            pk[k] = ((i & 127) << 17) | rows[e];
            atomicAdd(&cnt[bk[k]], 1);
        } else bk[k] = -1;
    }
    __syncthreads();
    for (int i = threadIdx.x; i < NBUCK; i += 256) {
        int c = cnt[i];
        basep[i] = c ? atomicAdd(&ccur[i], c) : 0;
        cnt[i] = 0;
    }
    __syncthreads();
    #pragma unroll
    for (int k = 0; k < K; ++k) {
        if (bk[k] >= 0) {
            int pos = basep[bk[k]] + atomicAdd(&cnt[bk[k]], 1);
            if (pos < BCAP)
                tmp[(size_t)bk[k] * BCAP + pos] = pk[k];
        }
    }
}

// Fine sort: stage bucket in LDS, hist+scan -> item_beg/item_end, scatter nbr.
__global__ __launch_bounds__(256) void fine_sort_kernel(
        const int* __restrict__ tmp, const int* __restrict__ ccur,
        int* __restrict__ item_beg, int* __restrict__ item_end,
        int* __restrict__ nbr) {
    __shared__ int stage[BCAP];    // 24 KB
    __shared__ int hist[128];
    __shared__ int scn[128];
    __shared__ int curs[128];
    int b = blockIdx.x, t = threadIdx.x;
    int n = ccur[b]; if (n > BCAP) n = BCAP;
    const int* src = tmp + (size_t)b * BCAP;
    if (t < 128) hist[t] = 0;
    __syncthreads();
    for (int p = t; p < n; p += 256) {
        int q = src[p];
        stage[p] = q;
        atomicAdd(&hist[q >> 17], 1);
    }
    __syncthreads();
    if (t < 128) scn[t] = hist[t];
    __syncthreads();
    for (int off = 1; off < 128; off <<= 1) {
        int x = (t < 128 && t >= off) ? scn[t - off] : 0;
        __syncthreads();
        if (t < 128) scn[t] += x;
        __syncthreads();
    }
    if (t < 128) {
        int excl = scn[t] - hist[t];
        curs[t] = excl;
        int gi = (b << 7) + t;
        if (gi < N_ITEMS) {
            item_beg[gi] = b * BCAP + excl;
            item_end[gi] = b * BCAP + excl + hist[t];
        }
    }
    __syncthreads();
    int* dst = nbr + (size_t)b * BCAP;
    for (int p = t; p < n; p += 256) {
        int q = stage[p];
        int pos = atomicAdd(&curs[q >> 17], 1);
        dst[pos] = q & 0x1FFFF;
    }
}

// Scaled conversion: srcS[r] = bf16(inv[r] * embeds[r]); invrow[r] = inv[r].
__global__ __launch_bounds__(256) void conv_scale_kernel(
        const float* __restrict__ embeds, const int* __restrict__ user_ptr,
        const int* __restrict__ item_beg, const int* __restrict__ item_end,
        unsigned* __restrict__ ebfS, unsigned* __restrict__ bb1,
        float* __restrict__ invrow) {
    int gid = blockIdx.x * blockDim.x + threadIdx.x;
    int row = gid >> 4, fl = gid & 15;
    if (row > N_TOT) return;
    if (row == N_TOT) {   // zero row
        *(uint2*)(ebfS + (size_t)row * 32 + fl * 2) = make_uint2(0u, 0u);
        *(uint2*)(bb1  + (size_t)row * 32 + fl * 2) = make_uint2(0u, 0u);
        if (fl == 0) invrow[row] = 0.f;
        return;
    }
    int deg;
    if (row < N_USERS) deg = user_ptr[row + 1] - user_ptr[row];
    else { int i = row - N_USERS; deg = item_end[i] - item_beg[i]; }
    float inv = (deg > 0) ? (float)(1.0 / sqrt((double)deg)) : 0.f;
    float4 v = *(const float4*)(embeds + (size_t)row * D + fl * 4);
    uint2 o;
    o.x = packbf(inv * v.x, inv * v.y);
    o.y = packbf(inv * v.z, inv * v.w);
    *(uint2*)(ebfS + (size_t)row * 32 + fl * 2) = o;
    if (fl == 0) invrow[row] = inv;
}

// ---------------- propagation (layers 1,2: all rows) ----------------
// XCD-specialized: blockIdx%8 roles 0-3 -> user destinations (gather the
// 6.4 MB item table), roles 4-7 -> item destinations (gather the 12.8 MB
// user table). Each XCD's L2 then holds only one source table.
#define UB_PER_ROLE 6250   // 25000 user blocks / 4 roles
#define IB_PER_ROLE 3125   // 12500 item blocks / 4 roles
__global__ __launch_bounds__(256) void agg_kernel(
        const unsigned* __restrict__ gsrc,   // scaled bf16 rows, 32 uints/row
        float* __restrict__ nxt, unsigned* __restrict__ nxtb,
        const float* __restrict__ invrow,
        const unsigned char* __restrict__ flags,
        const int* __restrict__ user_ptr, const unsigned short* __restrict__ cols16,
        const int* __restrict__ item_beg, const int* __restrict__ item_end,
        const int* __restrict__ nbr) {
    int role = (int)(blockIdx.x & 7);
    int sub  = (int)(blockIdx.x >> 3);
    int lw   = (int)(threadIdx.x >> 6);
    int lane = (int)(threadIdx.x & 63);
    int g  = lane >> 3;
    int fl = lane & 7;

    int dest, s, epos, dummy;
    const unsigned* sb;
    bool is_user = role < 4;
    if (is_user) {
        int ub = role * UB_PER_ROLE + sub;
        int u = ub * 4 + lw;
        if (u >= N_USERS) return;
        dest = u;
        s = user_ptr[u]; epos = user_ptr[u + 1];
        sb = gsrc + (size_t)N_USERS * 32; dummy = N_ITEMS;   // item table
    } else {
        int ib = (role - 4) * IB_PER_ROLE + sub;
        if (ib >= 12500) return;
        int it = ib * 4 + lw;
        if (it >= N_ITEMS) return;
        dest = N_USERS + it;
        s = item_beg[it]; epos = item_end[it];
        sb = gsrc; dummy = N_TOT;                            // user table
    }

    v2f a0 = {0.f, 0.f}, a1 = {0.f, 0.f}, a2 = {0.f, 0.f}, a3 = {0.f, 0.f};

    for (int base = s; base < epos; base += 64) {
        int cnt = epos - base; if (cnt > 64) cnt = 64;
        int col = dummy;
        if (lane < cnt)
            col = is_user ? (int)cols16[base + lane] : nbr[base + lane];
        int tcount = (cnt + 7) >> 3;
        #pragma unroll 4
        for (int t = 0; t < tcount; ++t) {
            int c = __shfl(col, 8 * t + g);
            uint4 q = *(const uint4*)(sb + (size_t)c * 32 + fl * 4);
            v2f p0 = {__uint_as_float(q.x << 16), __uint_as_float(q.x & 0xFFFF0000u)};
            v2f p1 = {__uint_as_float(q.y << 16), __uint_as_float(q.y & 0xFFFF0000u)};
            v2f p2 = {__uint_as_float(q.z << 16), __uint_as_float(q.z & 0xFFFF0000u)};
            v2f p3 = {__uint_as_float(q.w << 16), __uint_as_float(q.w & 0xFFFF0000u)};
            a0 += p0; a1 += p1; a2 += p2; a3 += p3;
        }
    }
    float acc[8] = {a0.x, a0.y, a1.x, a1.y, a2.x, a2.y, a3.x, a3.y};
    #pragma unroll
    for (int j = 0; j < 8; ++j) {
        acc[j] += __shfl_xor(acc[j], 8);
        acc[j] += __shfl_xor(acc[j], 16);
        acc[j] += __shfl_xor(acc[j], 32);
    }
    if (lane < 8) {
        float inv = invrow[dest];
        float f[8];
        #pragma unroll
        for (int j = 0; j < 8; ++j) f[j] = inv * acc[j];
        uint4 o;
        o.x = packbf(inv * f[0], inv * f[1]); o.y = packbf(inv * f[2], inv * f[3]);
        o.z = packbf(inv * f[4], inv * f[5]); o.w = packbf(inv * f[6], inv * f[7]);
        *(uint4*)(nxtb + (size_t)dest * 32 + fl * 4) = o;
        if (flags[dest]) {
            size_t ro = (size_t)dest * D + fl * 8;
            *(float4*)(nxt + ro)     = make_float4(f[0], f[1], f[2], f[3]);
            *(float4*)(nxt + ro + 4) = make_float4(f[4], f[5], f[6], f[7]);
        }
    }
}

// ---------------- layer 3 fused with epilogue: only output slots ----------------
__global__ __launch_bounds__(256) void agg3_fused_kernel(
        const unsigned* __restrict__ gsrc,
        const float* __restrict__ e0, const float* __restrict__ e1,
        const float* __restrict__ e2, const float* __restrict__ invrow,
        const int* __restrict__ users, const int* __restrict__ pos,
        const int* __restrict__ neg,
        const int* __restrict__ user_ptr, const unsigned short* __restrict__ cols16,
        const int* __restrict__ item_beg, const int* __restrict__ item_end,
        const int* __restrict__ nbr,
        float* __restrict__ out, int B) {
    int slot = (int)((blockIdx.x * blockDim.x + threadIdx.x) >> 6);
    int lane = (int)(threadIdx.x & 63);
    if (slot >= 3 * B) return;
    int g  = lane >> 3;
    int fl = lane & 7;

    int row;
    if (slot < B)          row = users[slot];
    else if (slot < 2 * B) row = N_USERS + pos[slot - B];
    else                   row = N_USERS + neg[slot - 2 * B];

    bool is_user = row < N_USERS;
    int s, epos, dummy;
    const unsigned* sb;
    if (is_user) {
        s = user_ptr[row]; epos = user_ptr[row + 1];
        sb = gsrc + (size_t)N_USERS * 32; dummy = N_ITEMS;
    } else {
        int i = row - N_USERS; s = item_beg[i]; epos = item_end[i];
        sb = gsrc; dummy = N_TOT;
    }

    v2f a0 = {0.f, 0.f}, a1 = {0.f, 0.f}, a2 = {0.f, 0.f}, a3 = {0.f, 0.f};

    for (int base = s; base < epos; base += 64) {
        int cnt = epos - base; if (cnt > 64) cnt = 64;
        int col = dummy;
        if (lane < cnt)
            col = is_user ? (int)cols16[base + lane] : nbr[base + lane];
        int tcount = (cnt + 7) >> 3;
        #pragma unroll 4
        for (int t = 0; t < tcount; ++t) {
            int c = __shfl(col, 8 * t + g);
            uint4 q = *(const uint4*)(sb + (size_t)c * 32 + fl * 4);
            v2f p0 = {__uint_as_float(q.x << 16), __uint_as_float(q.x & 0xFFFF0000u)};
            v2f p1 = {__uint_as_float(q.y << 16), __uint_as_float(q.y & 0xFFFF0000u)};
            v2f p2 = {__uint_as_float(q.z << 16), __uint_as_float(q.z & 0xFFFF0000u)};
            v2f p3 = {__uint_as_float(q.w << 16), __uint_as_float(q.w & 0xFFFF0000u)};
            a0 += p0; a1 += p1; a2 += p2; a3 += p3;
        }
    }
    float acc[8] = {a0.x, a0.y, a1.x, a1.y, a2.x, a2.y, a3.x, a3.y};
    #pragma unroll
    for (int j = 0; j < 8; ++j) {
        acc[j] += __shfl_xor(acc[j], 8);
        acc[j] += __shfl_xor(acc[j], 16);
        acc[j] += __shfl_xor(acc[j], 32);
    }
    if (lane < 8) {
        float inv = invrow[row];
        size_t ro = (size_t)row * D + fl * 8;
        float4 x0 = *(const float4*)(e0 + ro), x1 = *(const float4*)(e0 + ro + 4);
        float4 y0 = *(const float4*)(e1 + ro), y1 = *(const float4*)(e1 + ro + 4);
        float4 z0 = *(const float4*)(e2 + ro), z1 = *(const float4*)(e2 + ro + 4);
        float4 r0, r1;
        r0.x = (x0.x + y0.x + z0.x + inv * acc[0]) * 0.25f;
        r0.y = (x0.y + y0.y + z0.y + inv * acc[1]) * 0.25f;
        r0.z = (x0.z + y0.z + z0.z + inv * acc[2]) * 0.25f;
        r0.w = (x0.w + y0.w + z0.w + inv * acc[3]) * 0.25f;
        r1.x = (x1.x + y1.x + z1.x + inv * acc[4]) * 0.25f;
        r1.y = (x1.y + y1.y + z1.y + inv * acc[5]) * 0.25f;
        r1.z = (x1.z + y1.z + z1.z + inv * acc[6]) * 0.25f;
        r1.w = (x1.w + y1.w + z1.w + inv * acc[7]) * 0.25f;
        size_t oo = (size_t)slot * D + fl * 8;
        *(float4*)(out + oo)     = r0;
        *(float4*)(out + oo + 4) = r1;
    }
}

extern "C" void kernel_launch(void* const* d_in, const int* in_sizes, int n_in,
                              void* d_out, int out_size, void* d_ws, size_t ws_size,
                              hipStream_t stream) {
    const float* embeds = (const float*)d_in[0];
    const int*   rows   = (const int*)d_in[2];
    const int*   cols   = (const int*)d_in[3];
    const int*   users  = (const int*)d_in[4];
    const int*   pos    = (const int*)d_in[5];
    const int*   neg    = (const int*)d_in[6];
    const int E2 = in_sizes[1];
    const int E  = E2 / 2;
    const int B  = in_sizes[4];

    char* ws = (char*)d_ws;
    size_t off = 0;
    auto alloc = [&](size_t bytes) { void* p = ws + off; off = (off + bytes + 255) & ~(size_t)255; return p; };
    float*    buf1     = (float*)   alloc((size_t)N_TOT * D * sizeof(float));     // flagged fp32 L1
    float*    buf2     = (float*)   alloc((size_t)N_TOT * D * sizeof(float));     // flagged fp32 L2
    unsigned* ebfS     = (unsigned*)alloc((size_t)(N_TOT + 1) * 32 * sizeof(unsigned)); // scaled bf16 (+zero row); reused as bb2
    unsigned* bb1      = (unsigned*)alloc((size_t)(N_TOT + 1) * 32 * sizeof(unsigned));
    int*      nbr      = (int*)     alloc((size_t)NBUCK * BCAP * sizeof(int));    // padded item CSR (user idx)
    unsigned short* cols16 = (unsigned short*)alloc((size_t)E * sizeof(unsigned short));
    int*      user_ptr = (int*)     alloc((size_t)(N_USERS + 1) * sizeof(int));
    int*      ccur     = (int*)     alloc((size_t)NBUCK * sizeof(int));
    int*      item_beg = (int*)     alloc((size_t)N_ITEMS * sizeof(int));
    int*      item_end = (int*)     alloc((size_t)N_ITEMS * sizeof(int));
    float*    invrow   = (float*)   alloc((size_t)(N_TOT + 1) * sizeof(float));
    unsigned char* flags = (unsigned char*)alloc((size_t)N_TOT);
    int*      tmp      = (int*)buf1;   // alias: buf1 written only after fine_sort

    // --- preprocessing ---
    hipMemsetAsync(ccur, 0, (size_t)NBUCK * sizeof(int), stream);
    hipMemsetAsync(flags, 0, (size_t)N_TOT, stream);
    pre_misc_kernel<<<BS_B + (3 * B + 255) / 256, 256, 0, stream>>>(
        rows, user_ptr, E, users, pos, neg, flags, B);
    coarse_scatter_kernel<<<(E + 4095) / 4096, 256, 0, stream>>>(rows, cols, ccur, tmp, cols16, E);
    fine_sort_kernel<<<NBUCK, 256, 0, stream>>>(tmp, ccur, item_beg, item_end, nbr);
    conv_scale_kernel<<<((N_TOT + 1) * 16 + 255) / 256, 256, 0, stream>>>(
        embeds, user_ptr, item_beg, item_end, ebfS, bb1, invrow);

    // --- layers 1,2: XCD-specialized (roles 0-3 users, 4-7 items) ---
    const int blocks = 8 * UB_PER_ROLE;   // 50000
    agg_kernel<<<blocks, 256, 0, stream>>>(ebfS, buf1, bb1, invrow, flags, user_ptr,
                                           cols16, item_beg, item_end, nbr);
    agg_kernel<<<blocks, 256, 0, stream>>>(bb1, buf2, ebfS, invrow, flags, user_ptr,
                                           cols16, item_beg, item_end, nbr);  // bb2 = ebfS

    // --- layer 3 + epilogue fused: only the 3*B output slots ---
    agg3_fused_kernel<<<(3 * B + 3) / 4, 256, 0, stream>>>(
        ebfS, embeds, buf1, buf2, invrow, users, pos, neg,
        user_ptr, cols16, item_beg, item_end, nbr, (float*)d_out, B);
}

// Round 9
// 338.848 us; speedup vs baseline: 1.2364x; 1.2364x over previous
//
#include <hip/hip_runtime.h>
#include <hip/hip_bf16.h>

#define N_USERS 100000
#define N_ITEMS 50000
#define N_TOT   150000
#define D       64
#define NBUCK   ((N_ITEMS + 127) >> 7)   // 391 coarse buckets of 128 items
#define BCAP    6144                     // bucket capacity
#define CONVU_B 391                      // ceil(100000/256): user conv+ptr blocks
#define FLAG_B  48                       // ceil(3*4096/256)

typedef float v2f __attribute__((ext_vector_type(2)));

// ---------------- helpers ----------------
__device__ __forceinline__ unsigned bf16rn(float f) {        // fp32 -> bf16 bits (RNE)
    unsigned x = __float_as_uint(f);
    return (x + 0x7FFFu + ((x >> 16) & 1u)) >> 16;
}
__device__ __forceinline__ unsigned packbf(float a, float b) {
    return bf16rn(a) | (bf16rn(b) << 16);
}
__device__ __forceinline__ int lower_bound(const int* __restrict__ a, int n, int key) {
    int lo = 0, hi = n;
    while (lo < hi) {
        int mid = (lo + hi) >> 1;
        if (a[mid] < key) lo = mid + 1; else hi = mid;
    }
    return lo;
}

// ---------------- preprocessing kernel A ----------------
// Sections: [0,CONVU_B): user_ptr + user inv + user-row scaled bf16 conversion
//           [CONVU_B, +FLAG_B): flags
//           rest: coarse scatter into fixed-capacity buckets
__global__ __launch_bounds__(256) void preA_kernel(
        const float* __restrict__ embeds, const int* __restrict__ rows,
        const int* __restrict__ cols, int* __restrict__ user_ptr,
        unsigned* __restrict__ ebfS, float* __restrict__ invrow,
        const int* __restrict__ users, const int* __restrict__ pos,
        const int* __restrict__ neg, unsigned char* __restrict__ flags,
        int* __restrict__ ccur, int* __restrict__ tmp,
        unsigned short* __restrict__ cols16, int E, int B) {
    int b = blockIdx.x, t = threadIdx.x;
    if (b < CONVU_B) {
        __shared__ int ptr_s[257];
        __shared__ float inv_s[256];
        int base = b * 256;
        int r = base + t;
        int v = lower_bound(rows, E, r);
        ptr_s[t] = v;
        if (r <= N_USERS) user_ptr[r] = v;
        if (t == 0) ptr_s[256] = lower_bound(rows, E, base + 256);
        __syncthreads();
        if (r < N_USERS) {
            int deg = ptr_s[t + 1] - ptr_s[t];
            float inv = (deg > 0) ? (float)(1.0 / sqrt((double)deg)) : 0.f;
            inv_s[t] = inv;
            invrow[r] = inv;
        } else inv_s[t] = 0.f;
        __syncthreads();
        int fl = t & 15;
        #pragma unroll
        for (int i = 0; i < 16; ++i) {
            int lr = i * 16 + (t >> 4);
            int row = base + lr;
            if (row < N_USERS) {
                float inv = inv_s[lr];
                float4 v4 = *(const float4*)(embeds + (size_t)row * D + fl * 4);
                uint2 o;
                o.x = packbf(inv * v4.x, inv * v4.y);
                o.y = packbf(inv * v4.z, inv * v4.w);
                *(uint2*)(ebfS + (size_t)row * 32 + fl * 2) = o;
            }
        }
    } else if (b < CONVU_B + FLAG_B) {
        int k = (b - CONVU_B) * 256 + t;
        if (k < 3 * B) {
            int row;
            if (k < B)          row = users[k];
            else if (k < 2 * B) row = N_USERS + pos[k - B];
            else                row = N_USERS + neg[k - 2 * B];
            flags[row] = 1;
        }
    } else {
        __shared__ int cnt[NBUCK];
        __shared__ int basep[NBUCK];
        const int K = 16;
        int chunk = (b - CONVU_B - FLAG_B) * (256 * K);
        for (int i = t; i < NBUCK; i += 256) cnt[i] = 0;
        __syncthreads();
        int pk[K]; int bk[K];
        #pragma unroll
        for (int k = 0; k < K; ++k) {
            int e = chunk + k * 256 + t;
            if (e < E) {
                int i = cols[e] - N_USERS;
                cols16[e] = (unsigned short)i;
                bk[k] = i >> 7;
                pk[k] = ((i & 127) << 17) | rows[e];
                atomicAdd(&cnt[bk[k]], 1);
            } else bk[k] = -1;
        }
        __syncthreads();
        for (int i = t; i < NBUCK; i += 256) {
            int c = cnt[i];
            basep[i] = c ? atomicAdd(&ccur[i], c) : 0;
            cnt[i] = 0;
        }
        __syncthreads();
        #pragma unroll
        for (int k = 0; k < K; ++k) {
            if (bk[k] >= 0) {
                int pos2 = basep[bk[k]] + atomicAdd(&cnt[bk[k]], 1);
                if (pos2 < BCAP)
                    tmp[(size_t)bk[k] * BCAP + pos2] = pk[k];
            }
        }
    }
}

// ---------------- preprocessing kernel B ----------------
// Blocks [0,NBUCK): fine sort (LDS-staged) + item inv + item-row conversion.
// Block NBUCK: zero row init.
__global__ __launch_bounds__(256) void preB_kernel(
        const int* __restrict__ tmp, const int* __restrict__ ccur,
        const float* __restrict__ embeds,
        int* __restrict__ item_beg, int* __restrict__ item_end,
        int* __restrict__ nbr, unsigned* __restrict__ ebfS,
        unsigned* __restrict__ bb1, float* __restrict__ invrow) {
    int b = blockIdx.x, t = threadIdx.x;
    if (b == NBUCK) {
        if (t < 16) {
            *(uint2*)(ebfS + (size_t)N_TOT * 32 + t * 2) = make_uint2(0u, 0u);
            *(uint2*)(bb1  + (size_t)N_TOT * 32 + t * 2) = make_uint2(0u, 0u);
        }
        if (t == 0) invrow[N_TOT] = 0.f;
        return;
    }
    __shared__ int stage[BCAP];    // 24 KB
    __shared__ int hist[128];
    __shared__ int scn[128];
    __shared__ int curs[128];
    __shared__ float inv_s[128];
    int n = ccur[b]; if (n > BCAP) n = BCAP;
    const int* src = tmp + (size_t)b * BCAP;
    if (t < 128) hist[t] = 0;
    __syncthreads();
    for (int p = t; p < n; p += 256) {
        int q = src[p];
        stage[p] = q;
        atomicAdd(&hist[q >> 17], 1);
    }
    __syncthreads();
    if (t < 128) scn[t] = hist[t];
    __syncthreads();
    for (int off = 1; off < 128; off <<= 1) {
        int x = (t < 128 && t >= off) ? scn[t - off] : 0;
        __syncthreads();
        if (t < 128) scn[t] += x;
        __syncthreads();
    }
    if (t < 128) {
        int excl = scn[t] - hist[t];
        curs[t] = excl;
        int gi = (b << 7) + t;
        float inv = (hist[t] > 0) ? (float)(1.0 / sqrt((double)hist[t])) : 0.f;
        inv_s[t] = inv;
        if (gi < N_ITEMS) {
            item_beg[gi] = b * BCAP + excl;
            item_end[gi] = b * BCAP + excl + hist[t];
            invrow[N_USERS + gi] = inv;
        }
    }
    __syncthreads();
    int* dst = nbr + (size_t)b * BCAP;
    for (int p = t; p < n; p += 256) {
        int q = stage[p];
        int pos = atomicAdd(&curs[q >> 17], 1);
        dst[pos] = q & 0x1FFFF;
    }
    // item-row scaled conversion (128 rows of this bucket)
    int fl = t & 15;
    #pragma unroll
    for (int i = 0; i < 8; ++i) {
        int lr = i * 16 + (t >> 4);
        int gi = (b << 7) + lr;
        if (gi < N_ITEMS) {
            int row = N_USERS + gi;
            float inv = inv_s[lr];
            float4 v4 = *(const float4*)(embeds + (size_t)row * D + fl * 4);
            uint2 o;
            o.x = packbf(inv * v4.x, inv * v4.y);
            o.y = packbf(inv * v4.z, inv * v4.w);
            *(uint2*)(ebfS + (size_t)row * 32 + fl * 2) = o;
        }
    }
}

// ---------------- propagation (layers 1,2: all rows) ----------------
// One wave per destination row; 8 lanes/edge (uint4 = 8 bf16), 8 edges in
// flight; metadata preloaded 64-wide, broadcast via shfl. Sources are
// inv-scaled bf16 rows -> plain accumulation, no per-edge weight.
__global__ __launch_bounds__(256) void agg_kernel(
        const unsigned* __restrict__ gsrc,   // scaled bf16 rows, 32 uints/row
        float* __restrict__ nxt, unsigned* __restrict__ nxtb,
        const float* __restrict__ invrow,
        const unsigned char* __restrict__ flags,
        const int* __restrict__ user_ptr, const unsigned short* __restrict__ cols16,
        const int* __restrict__ item_beg, const int* __restrict__ item_end,
        const int* __restrict__ nbr) {
    int wave = (int)((blockIdx.x * blockDim.x + threadIdx.x) >> 6);
    int lane = (int)(threadIdx.x & 63);
    if (wave >= N_TOT) return;
    int g  = lane >> 3;
    int fl = lane & 7;

    bool is_user = wave < N_USERS;
    int s, epos, dummy;
    const unsigned* sb;
    if (is_user) {
        s = user_ptr[wave]; epos = user_ptr[wave + 1];
        sb = gsrc + (size_t)N_USERS * 32; dummy = N_ITEMS;
    } else {
        int i = wave - N_USERS; s = item_beg[i]; epos = item_end[i];
        sb = gsrc; dummy = N_TOT;
    }

    v2f a0 = {0.f, 0.f}, a1 = {0.f, 0.f}, a2 = {0.f, 0.f}, a3 = {0.f, 0.f};

    for (int base = s; base < epos; base += 64) {
        int cnt = epos - base; if (cnt > 64) cnt = 64;
        int col = dummy;
        if (lane < cnt)
            col = is_user ? (int)cols16[base + lane] : nbr[base + lane];
        int tcount = (cnt + 7) >> 3;
        #pragma unroll 4
        for (int t = 0; t < tcount; ++t) {
            int c = __shfl(col, 8 * t + g);
            uint4 q = *(const uint4*)(sb + (size_t)c * 32 + fl * 4);
            v2f p0 = {__uint_as_float(q.x << 16), __uint_as_float(q.x & 0xFFFF0000u)};
            v2f p1 = {__uint_as_float(q.y << 16), __uint_as_float(q.y & 0xFFFF0000u)};
            v2f p2 = {__uint_as_float(q.z << 16), __uint_as_float(q.z & 0xFFFF0000u)};
            v2f p3 = {__uint_as_float(q.w << 16), __uint_as_float(q.w & 0xFFFF0000u)};
            a0 += p0; a1 += p1; a2 += p2; a3 += p3;
        }
    }
    float acc[8] = {a0.x, a0.y, a1.x, a1.y, a2.x, a2.y, a3.x, a3.y};
    #pragma unroll
    for (int j = 0; j < 8; ++j) {
        acc[j] += __shfl_xor(acc[j], 8);
        acc[j] += __shfl_xor(acc[j], 16);
        acc[j] += __shfl_xor(acc[j], 32);
    }
    if (lane < 8) {
        float inv = invrow[wave];
        float f[8];
        #pragma unroll
        for (int j = 0; j < 8; ++j) f[j] = inv * acc[j];
        uint4 o;
        o.x = packbf(inv * f[0], inv * f[1]); o.y = packbf(inv * f[2], inv * f[3]);
        o.z = packbf(inv * f[4], inv * f[5]); o.w = packbf(inv * f[6], inv * f[7]);
        *(uint4*)(nxtb + (size_t)wave * 32 + fl * 4) = o;
        if (flags[wave]) {
            size_t ro = (size_t)wave * D + fl * 8;
            *(float4*)(nxt + ro)     = make_float4(f[0], f[1], f[2], f[3]);
            *(float4*)(nxt + ro + 4) = make_float4(f[4], f[5], f[6], f[7]);
        }
    }
}

// ---------------- layer 3 fused with epilogue: only output slots ----------------
__global__ __launch_bounds__(256) void agg3_fused_kernel(
        const unsigned* __restrict__ gsrc,
        const float* __restrict__ e0, const float* __restrict__ e1,
        const float* __restrict__ e2, const float* __restrict__ invrow,
        const int* __restrict__ users, const int* __restrict__ pos,
        const int* __restrict__ neg,
        const int* __restrict__ user_ptr, const unsigned short* __restrict__ cols16,
        const int* __restrict__ item_beg, const int* __restrict__ item_end,
        const int* __restrict__ nbr,
        float* __restrict__ out, int B) {
    int slot = (int)((blockIdx.x * blockDim.x + threadIdx.x) >> 6);
    int lane = (int)(threadIdx.x & 63);
    if (slot >= 3 * B) return;
    int g  = lane >> 3;
    int fl = lane & 7;

    int row;
    if (slot < B)          row = users[slot];
    else if (slot < 2 * B) row = N_USERS + pos[slot - B];
    else                   row = N_USERS + neg[slot - 2 * B];

    bool is_user = row < N_USERS;
    int s, epos, dummy;
    const unsigned* sb;
    if (is_user) {
        s = user_ptr[row]; epos = user_ptr[row + 1];
        sb = gsrc + (size_t)N_USERS * 32; dummy = N_ITEMS;
    } else {
        int i = row - N_USERS; s = item_beg[i]; epos = item_end[i];
        sb = gsrc; dummy = N_TOT;
    }

    v2f a0 = {0.f, 0.f}, a1 = {0.f, 0.f}, a2 = {0.f, 0.f}, a3 = {0.f, 0.f};

    for (int base = s; base < epos; base += 64) {
        int cnt = epos - base; if (cnt > 64) cnt = 64;
        int col = dummy;
        if (lane < cnt)
            col = is_user ? (int)cols16[base + lane] : nbr[base + lane];
        int tcount = (cnt + 7) >> 3;
        #pragma unroll 4
        for (int t = 0; t < tcount; ++t) {
            int c = __shfl(col, 8 * t + g);
            uint4 q = *(const uint4*)(sb + (size_t)c * 32 + fl * 4);
            v2f p0 = {__uint_as_float(q.x << 16), __uint_as_float(q.x & 0xFFFF0000u)};
            v2f p1 = {__uint_as_float(q.y << 16), __uint_as_float(q.y & 0xFFFF0000u)};
            v2f p2 = {__uint_as_float(q.z << 16), __uint_as_float(q.z & 0xFFFF0000u)};
            v2f p3 = {__uint_as_float(q.w << 16), __uint_as_float(q.w & 0xFFFF0000u)};
            a0 += p0; a1 += p1; a2 += p2; a3 += p3;
        }
    }
    float acc[8] = {a0.x, a0.y, a1.x, a1.y, a2.x, a2.y, a3.x, a3.y};
    #pragma unroll
    for (int j = 0; j < 8; ++j) {
        acc[j] += __shfl_xor(acc[j], 8);
        acc[j] += __shfl_xor(acc[j], 16);
        acc[j] += __shfl_xor(acc[j], 32);
    }
    if (lane < 8) {
        float inv = invrow[row];
        size_t ro = (size_t)row * D + fl * 8;
        float4 x0 = *(const float4*)(e0 + ro), x1 = *(const float4*)(e0 + ro + 4);
        float4 y0 = *(const float4*)(e1 + ro), y1 = *(const float4*)(e1 + ro + 4);
        float4 z0 = *(const float4*)(e2 + ro), z1 = *(const float4*)(e2 + ro + 4);
        float4 r0, r1;
        r0.x = (x0.x + y0.x + z0.x + inv * acc[0]) * 0.25f;
        r0.y = (x0.y + y0.y + z0.y + inv * acc[1]) * 0.25f;
        r0.z = (x0.z + y0.z + z0.z + inv * acc[2]) * 0.25f;
        r0.w = (x0.w + y0.w + z0.w + inv * acc[3]) * 0.25f;
        r1.x = (x1.x + y1.x + z1.x + inv * acc[4]) * 0.25f;
        r1.y = (x1.y + y1.y + z1.y + inv * acc[5]) * 0.25f;
        r1.z = (x1.z + y1.z + z1.z + inv * acc[6]) * 0.25f;
        r1.w = (x1.w + y1.w + z1.w + inv * acc[7]) * 0.25f;
        size_t oo = (size_t)slot * D + fl * 8;
        *(float4*)(out + oo)     = r0;
        *(float4*)(out + oo + 4) = r1;
    }
}

extern "C" void kernel_launch(void* const* d_in, const int* in_sizes, int n_in,
                              void* d_out, int out_size, void* d_ws, size_t ws_size,
                              hipStream_t stream) {
    const float* embeds = (const float*)d_in[0];
    const int*   rows   = (const int*)d_in[2];
    const int*   cols   = (const int*)d_in[3];
    const int*   users  = (const int*)d_in[4];
    const int*   pos    = (const int*)d_in[5];
    const int*   neg    = (const int*)d_in[6];
    const int E2 = in_sizes[1];
    const int E  = E2 / 2;
    const int B  = in_sizes[4];

    char* ws = (char*)d_ws;
    size_t off = 0;
    auto alloc = [&](size_t bytes) { void* p = ws + off; off = (off + bytes + 255) & ~(size_t)255; return p; };
    float*    buf1     = (float*)   alloc((size_t)N_TOT * D * sizeof(float));     // flagged fp32 L1
    float*    buf2     = (float*)   alloc((size_t)N_TOT * D * sizeof(float));     // flagged fp32 L2
    unsigned* ebfS     = (unsigned*)alloc((size_t)(N_TOT + 1) * 32 * sizeof(unsigned)); // scaled bf16 (+zero row); reused as bb2
    unsigned* bb1      = (unsigned*)alloc((size_t)(N_TOT + 1) * 32 * sizeof(unsigned));
    int*      nbr      = (int*)     alloc((size_t)NBUCK * BCAP * sizeof(int));    // padded item CSR (user idx)
    unsigned short* cols16 = (unsigned short*)alloc((size_t)E * sizeof(unsigned short));
    int*      user_ptr = (int*)     alloc((size_t)(N_USERS + 1) * sizeof(int));
    int*      ccur     = (int*)     alloc((size_t)NBUCK * sizeof(int));
    int*      item_beg = (int*)     alloc((size_t)N_ITEMS * sizeof(int));
    int*      item_end = (int*)     alloc((size_t)N_ITEMS * sizeof(int));
    float*    invrow   = (float*)   alloc((size_t)(N_TOT + 1) * sizeof(float));
    unsigned char* flags = (unsigned char*)alloc((size_t)N_TOT);
    int*      tmp      = (int*)buf1;   // alias: buf1 written only after preB

    // --- preprocessing (2 fused kernels) ---
    hipMemsetAsync(ccur, 0, (size_t)NBUCK * sizeof(int), stream);
    hipMemsetAsync(flags, 0, (size_t)N_TOT, stream);
    const int scatB = (E + 4095) / 4096;
    preA_kernel<<<CONVU_B + FLAG_B + scatB, 256, 0, stream>>>(
        embeds, rows, cols, user_ptr, ebfS, invrow, users, pos, neg, flags,
        ccur, tmp, cols16, E, B);
    preB_kernel<<<NBUCK + 1, 256, 0, stream>>>(
        tmp, ccur, embeds, item_beg, item_end, nbr, ebfS, bb1, invrow);

    // --- layers 1,2: all rows (scaled bf16 out + flagged fp32 out) ---
    const int blocks = (N_TOT + 3) / 4;
    agg_kernel<<<blocks, 256, 0, stream>>>(ebfS, buf1, bb1, invrow, flags, user_ptr,
                                           cols16, item_beg, item_end, nbr);
    agg_kernel<<<blocks, 256, 0, stream>>>(bb1, buf2, ebfS, invrow, flags, user_ptr,
                                           cols16, item_beg, item_end, nbr);  // bb2 = ebfS

    // --- layer 3 + epilogue fused: only the 3*B output slots ---
    agg3_fused_kernel<<<(3 * B + 3) / 4, 256, 0, stream>>>(
        ebfS, embeds, buf1, buf2, invrow, users, pos, neg,
        user_ptr, cols16, item_beg, item_end, nbr, (float*)d_out, B);
}

// Round 10
// 331.283 us; speedup vs baseline: 1.2646x; 1.0228x over previous
//
#include <hip/hip_runtime.h>
#include <hip/hip_bf16.h>

#define N_USERS 100000
#define N_ITEMS 50000
#define N_TOT   150000
#define D       64
#define NBUCK   ((N_ITEMS + 255) >> 8)   // 196 coarse buckets of 256 items
#define BCAP    12288                    // bucket capacity (mean ~10.2K, +18 sigma)
#define CONVU_B 391                      // ceil(100000/256): user conv+ptr blocks
#define FLAG_B  48                       // ceil(3*4096/256)
#define SCAT_K  32                       // edges per thread in scatter section

typedef float v2f __attribute__((ext_vector_type(2)));

// ---------------- helpers ----------------
__device__ __forceinline__ unsigned bf16rn(float f) {        // fp32 -> bf16 bits (RNE)
    unsigned x = __float_as_uint(f);
    return (x + 0x7FFFu + ((x >> 16) & 1u)) >> 16;
}
__device__ __forceinline__ unsigned packbf(float a, float b) {
    return bf16rn(a) | (bf16rn(b) << 16);
}
__device__ __forceinline__ int lower_bound(const int* __restrict__ a, int n, int key) {
    int lo = 0, hi = n;
    while (lo < hi) {
        int mid = (lo + hi) >> 1;
        if (a[mid] < key) lo = mid + 1; else hi = mid;
    }
    return lo;
}

// ---------------- preprocessing kernel A ----------------
// Sections: [0,CONVU_B): user_ptr + user inv + user-row scaled bf16 conversion
//           [CONVU_B, +FLAG_B): flags
//           rest: LDS-buffered coarse scatter (K=32, 256-item buckets)
__global__ __launch_bounds__(256) void preA_kernel(
        const float* __restrict__ embeds, const int* __restrict__ rows,
        const int* __restrict__ cols, int* __restrict__ user_ptr,
        unsigned* __restrict__ ebfS, float* __restrict__ invrow,
        const int* __restrict__ users, const int* __restrict__ pos,
        const int* __restrict__ neg, unsigned char* __restrict__ flags,
        int* __restrict__ ccur, int* __restrict__ tmp,
        unsigned short* __restrict__ cols16, int E, int B) {
    int b = blockIdx.x, t = threadIdx.x;
    if (b < CONVU_B) {
        __shared__ int ptr_s[257];
        __shared__ float inv_s[256];
        int base = b * 256;
        int r = base + t;
        int v = lower_bound(rows, E, r);
        ptr_s[t] = v;
        if (r <= N_USERS) user_ptr[r] = v;
        if (t == 0) ptr_s[256] = lower_bound(rows, E, base + 256);
        __syncthreads();
        if (r < N_USERS) {
            int deg = ptr_s[t + 1] - ptr_s[t];
            float inv = (deg > 0) ? (float)(1.0 / sqrt((double)deg)) : 0.f;
            inv_s[t] = inv;
            invrow[r] = inv;
        } else inv_s[t] = 0.f;
        __syncthreads();
        int fl = t & 15;
        #pragma unroll
        for (int i = 0; i < 16; ++i) {
            int lr = i * 16 + (t >> 4);
            int row = base + lr;
            if (row < N_USERS) {
                float inv = inv_s[lr];
                float4 v4 = *(const float4*)(embeds + (size_t)row * D + fl * 4);
                uint2 o;
                o.x = packbf(inv * v4.x, inv * v4.y);
                o.y = packbf(inv * v4.z, inv * v4.w);
                *(uint2*)(ebfS + (size_t)row * 32 + fl * 2) = o;
            }
        }
    } else if (b < CONVU_B + FLAG_B) {
        int k = (b - CONVU_B) * 256 + t;
        if (k < 3 * B) {
            int row;
            if (k < B)          row = users[k];
            else if (k < 2 * B) row = N_USERS + pos[k - B];
            else                row = N_USERS + neg[k - 2 * B];
            flags[row] = 1;
        }
    } else {
        __shared__ int ebuf[256 * SCAT_K];            // 32 KB payloads
        __shared__ unsigned char bbuf[256 * SCAT_K];  // 8 KB bucket ids
        __shared__ int cnt[NBUCK];
        __shared__ int basep[NBUCK];
        int chunk = (b - CONVU_B - FLAG_B) * (256 * SCAT_K);
        if (t < NBUCK) cnt[t] = 0;
        __syncthreads();
        #pragma unroll 4
        for (int k = 0; k < SCAT_K; ++k) {
            int e = chunk + k * 256 + t;
            int idx = k * 256 + t;
            if (e < E) {
                int i = cols[e] - N_USERS;
                cols16[e] = (unsigned short)i;
                int bu = i >> 8;
                ebuf[idx] = ((i & 255) << 17) | rows[e];
                bbuf[idx] = (unsigned char)bu;
                atomicAdd(&cnt[bu], 1);
            } else bbuf[idx] = 255;                    // invalid (>195)
        }
        __syncthreads();
        if (t < NBUCK) {
            int c = cnt[t];
            basep[t] = c ? atomicAdd(&ccur[t], c) : 0;
            cnt[t] = 0;
        }
        __syncthreads();
        #pragma unroll 4
        for (int k = 0; k < SCAT_K; ++k) {
            int idx = k * 256 + t;
            int bu = bbuf[idx];
            if (bu < NBUCK) {
                int pos2 = basep[bu] + atomicAdd(&cnt[bu], 1);
                if (pos2 < BCAP)
                    tmp[(size_t)bu * BCAP + pos2] = ebuf[idx];
            }
        }
    }
}

// ---------------- preprocessing kernel B ----------------
// Blocks [0,NBUCK): fine sort (LDS-staged) + item inv + item-row conversion.
// Block NBUCK: zero row init.
__global__ __launch_bounds__(256) void preB_kernel(
        const int* __restrict__ tmp, const int* __restrict__ ccur,
        const float* __restrict__ embeds,
        int* __restrict__ item_beg, int* __restrict__ item_end,
        int* __restrict__ nbr, unsigned* __restrict__ ebfS,
        unsigned* __restrict__ bb1, float* __restrict__ invrow) {
    int b = blockIdx.x, t = threadIdx.x;
    if (b == NBUCK) {
        if (t < 16) {
            *(uint2*)(ebfS + (size_t)N_TOT * 32 + t * 2) = make_uint2(0u, 0u);
            *(uint2*)(bb1  + (size_t)N_TOT * 32 + t * 2) = make_uint2(0u, 0u);
        }
        if (t == 0) invrow[N_TOT] = 0.f;
        return;
    }
    __shared__ int stage[BCAP];    // 48 KB
    __shared__ int hist[256];
    __shared__ int scn[256];
    __shared__ int curs[256];
    __shared__ float inv_s[256];
    int n = ccur[b]; if (n > BCAP) n = BCAP;
    const int* src = tmp + (size_t)b * BCAP;
    hist[t] = 0;
    __syncthreads();
    for (int p = t; p < n; p += 256) {
        int q = src[p];
        stage[p] = q;
        atomicAdd(&hist[q >> 17], 1);
    }
    __syncthreads();
    scn[t] = hist[t];
    __syncthreads();
    for (int off = 1; off < 256; off <<= 1) {
        int x = (t >= off) ? scn[t - off] : 0;
        __syncthreads();
        scn[t] += x;
        __syncthreads();
    }
    {
        int excl = scn[t] - hist[t];
        curs[t] = excl;
        int gi = (b << 8) + t;
        float inv = (hist[t] > 0) ? (float)(1.0 / sqrt((double)hist[t])) : 0.f;
        inv_s[t] = inv;
        if (gi < N_ITEMS) {
            item_beg[gi] = b * BCAP + excl;
            item_end[gi] = b * BCAP + excl + hist[t];
            invrow[N_USERS + gi] = inv;
        }
    }
    __syncthreads();
    int* dst = nbr + (size_t)b * BCAP;
    for (int p = t; p < n; p += 256) {
        int q = stage[p];
        int pos = atomicAdd(&curs[q >> 17], 1);
        dst[pos] = q & 0x1FFFF;
    }
    // item-row scaled conversion (256 rows of this bucket)
    int fl = t & 15;
    #pragma unroll
    for (int i = 0; i < 16; ++i) {
        int lr = i * 16 + (t >> 4);
        int gi = (b << 8) + lr;
        if (gi < N_ITEMS) {
            int row = N_USERS + gi;
            float inv = inv_s[lr];
            float4 v4 = *(const float4*)(embeds + (size_t)row * D + fl * 4);
            uint2 o;
            o.x = packbf(inv * v4.x, inv * v4.y);
            o.y = packbf(inv * v4.z, inv * v4.w);
            *(uint2*)(ebfS + (size_t)row * 32 + fl * 2) = o;
        }
    }
}

// ---------------- propagation (layers 1,2: all rows) ----------------
// One wave per destination row; 8 lanes/edge (uint4 = 8 bf16), 8 edges in
// flight; metadata preloaded 64-wide, broadcast via shfl. Sources are
// inv-scaled bf16 rows -> plain accumulation, no per-edge weight.
__global__ __launch_bounds__(256) void agg_kernel(
        const unsigned* __restrict__ gsrc,   // scaled bf16 rows, 32 uints/row
        float* __restrict__ nxt, unsigned* __restrict__ nxtb,
        const float* __restrict__ invrow,
        const unsigned char* __restrict__ flags,
        const int* __restrict__ user_ptr, const unsigned short* __restrict__ cols16,
        const int* __restrict__ item_beg, const int* __restrict__ item_end,
        const int* __restrict__ nbr) {
    int wave = (int)((blockIdx.x * blockDim.x + threadIdx.x) >> 6);
    int lane = (int)(threadIdx.x & 63);
    if (wave >= N_TOT) return;
    int g  = lane >> 3;
    int fl = lane & 7;

    bool is_user = wave < N_USERS;
    int s, epos, dummy;
    const unsigned* sb;
    if (is_user) {
        s = user_ptr[wave]; epos = user_ptr[wave + 1];
        sb = gsrc + (size_t)N_USERS * 32; dummy = N_ITEMS;
    } else {
        int i = wave - N_USERS; s = item_beg[i]; epos = item_end[i];
        sb = gsrc; dummy = N_TOT;
    }

    v2f a0 = {0.f, 0.f}, a1 = {0.f, 0.f}, a2 = {0.f, 0.f}, a3 = {0.f, 0.f};

    for (int base = s; base < epos; base += 64) {
        int cnt = epos - base; if (cnt > 64) cnt = 64;
        int col = dummy;
        if (lane < cnt)
            col = is_user ? (int)cols16[base + lane] : nbr[base + lane];
        int tcount = (cnt + 7) >> 3;
        #pragma unroll 4
        for (int t = 0; t < tcount; ++t) {
            int c = __shfl(col, 8 * t + g);
            uint4 q = *(const uint4*)(sb + (size_t)c * 32 + fl * 4);
            v2f p0 = {__uint_as_float(q.x << 16), __uint_as_float(q.x & 0xFFFF0000u)};
            v2f p1 = {__uint_as_float(q.y << 16), __uint_as_float(q.y & 0xFFFF0000u)};
            v2f p2 = {__uint_as_float(q.z << 16), __uint_as_float(q.z & 0xFFFF0000u)};
            v2f p3 = {__uint_as_float(q.w << 16), __uint_as_float(q.w & 0xFFFF0000u)};
            a0 += p0; a1 += p1; a2 += p2; a3 += p3;
        }
    }
    float acc[8] = {a0.x, a0.y, a1.x, a1.y, a2.x, a2.y, a3.x, a3.y};
    #pragma unroll
    for (int j = 0; j < 8; ++j) {
        acc[j] += __shfl_xor(acc[j], 8);
        acc[j] += __shfl_xor(acc[j], 16);
        acc[j] += __shfl_xor(acc[j], 32);
    }
    if (lane < 8) {
        float inv = invrow[wave];
        float f[8];
        #pragma unroll
        for (int j = 0; j < 8; ++j) f[j] = inv * acc[j];
        uint4 o;
        o.x = packbf(inv * f[0], inv * f[1]); o.y = packbf(inv * f[2], inv * f[3]);
        o.z = packbf(inv * f[4], inv * f[5]); o.w = packbf(inv * f[6], inv * f[7]);
        *(uint4*)(nxtb + (size_t)wave * 32 + fl * 4) = o;
        if (flags[wave]) {
            size_t ro = (size_t)wave * D + fl * 8;
            *(float4*)(nxt + ro)     = make_float4(f[0], f[1], f[2], f[3]);
            *(float4*)(nxt + ro + 4) = make_float4(f[4], f[5], f[6], f[7]);
        }
    }
}

// ---------------- layer 3 fused with epilogue: only output slots ----------------
__global__ __launch_bounds__(256) void agg3_fused_kernel(
        const unsigned* __restrict__ gsrc,
        const float* __restrict__ e0, const float* __restrict__ e1,
        const float* __restrict__ e2, const float* __restrict__ invrow,
        const int* __restrict__ users, const int* __restrict__ pos,
        const int* __restrict__ neg,
        const int* __restrict__ user_ptr, const unsigned short* __restrict__ cols16,
        const int* __restrict__ item_beg, const int* __restrict__ item_end,
        const int* __restrict__ nbr,
        float* __restrict__ out, int B) {
    int slot = (int)((blockIdx.x * blockDim.x + threadIdx.x) >> 6);
    int lane = (int)(threadIdx.x & 63);
    if (slot >= 3 * B) return;
    int g  = lane >> 3;
    int fl = lane & 7;

    int row;
    if (slot < B)          row = users[slot];
    else if (slot < 2 * B) row = N_USERS + pos[slot - B];
    else                   row = N_USERS + neg[slot - 2 * B];

    bool is_user = row < N_USERS;
    int s, epos, dummy;
    const unsigned* sb;
    if (is_user) {
        s = user_ptr[row]; epos = user_ptr[row + 1];
        sb = gsrc + (size_t)N_USERS * 32; dummy = N_ITEMS;
    } else {
        int i = row - N_USERS; s = item_beg[i]; epos = item_end[i];
        sb = gsrc; dummy = N_TOT;
    }

    v2f a0 = {0.f, 0.f}, a1 = {0.f, 0.f}, a2 = {0.f, 0.f}, a3 = {0.f, 0.f};

    for (int base = s; base < epos; base += 64) {
        int cnt = epos - base; if (cnt > 64) cnt = 64;
        int col = dummy;
        if (lane < cnt)
            col = is_user ? (int)cols16[base + lane] : nbr[base + lane];
        int tcount = (cnt + 7) >> 3;
        #pragma unroll 4
        for (int t = 0; t < tcount; ++t) {
            int c = __shfl(col, 8 * t + g);
            uint4 q = *(const uint4*)(sb + (size_t)c * 32 + fl * 4);
            v2f p0 = {__uint_as_float(q.x << 16), __uint_as_float(q.x & 0xFFFF0000u)};
            v2f p1 = {__uint_as_float(q.y << 16), __uint_as_float(q.y & 0xFFFF0000u)};
            v2f p2 = {__uint_as_float(q.z << 16), __uint_as_float(q.z & 0xFFFF0000u)};
            v2f p3 = {__uint_as_float(q.w << 16), __uint_as_float(q.w & 0xFFFF0000u)};
            a0 += p0; a1 += p1; a2 += p2; a3 += p3;
        }
    }
    float acc[8] = {a0.x, a0.y, a1.x, a1.y, a2.x, a2.y, a3.x, a3.y};
    #pragma unroll
    for (int j = 0; j < 8; ++j) {
        acc[j] += __shfl_xor(acc[j], 8);
        acc[j] += __shfl_xor(acc[j], 16);
        acc[j] += __shfl_xor(acc[j], 32);
    }
    if (lane < 8) {
        float inv = invrow[row];
        size_t ro = (size_t)row * D + fl * 8;
        float4 x0 = *(const float4*)(e0 + ro), x1 = *(const float4*)(e0 + ro + 4);
        float4 y0 = *(const float4*)(e1 + ro), y1 = *(const float4*)(e1 + ro + 4);
        float4 z0 = *(const float4*)(e2 + ro), z1 = *(const float4*)(e2 + ro + 4);
        float4 r0, r1;
        r0.x = (x0.x + y0.x + z0.x + inv * acc[0]) * 0.25f;
        r0.y = (x0.y + y0.y + z0.y + inv * acc[1]) * 0.25f;
        r0.z = (x0.z + y0.z + z0.z + inv * acc[2]) * 0.25f;
        r0.w = (x0.w + y0.w + z0.w + inv * acc[3]) * 0.25f;
        r1.x = (x1.x + y1.x + z1.x + inv * acc[4]) * 0.25f;
        r1.y = (x1.y + y1.y + z1.y + inv * acc[5]) * 0.25f;
        r1.z = (x1.z + y1.z + z1.z + inv * acc[6]) * 0.25f;
        r1.w = (x1.w + y1.w + z1.w + inv * acc[7]) * 0.25f;
        size_t oo = (size_t)slot * D + fl * 8;
        *(float4*)(out + oo)     = r0;
        *(float4*)(out + oo + 4) = r1;
    }
}

extern "C" void kernel_launch(void* const* d_in, const int* in_sizes, int n_in,
                              void* d_out, int out_size, void* d_ws, size_t ws_size,
                              hipStream_t stream) {
    const float* embeds = (const float*)d_in[0];
    const int*   rows   = (const int*)d_in[2];
    const int*   cols   = (const int*)d_in[3];
    const int*   users  = (const int*)d_in[4];
    const int*   pos    = (const int*)d_in[5];
    const int*   neg    = (const int*)d_in[6];
    const int E2 = in_sizes[1];
    const int E  = E2 / 2;
    const int B  = in_sizes[4];

    char* ws = (char*)d_ws;
    size_t off = 0;
    auto alloc = [&](size_t bytes) { void* p = ws + off; off = (off + bytes + 255) & ~(size_t)255; return p; };
    float*    buf1     = (float*)   alloc((size_t)N_TOT * D * sizeof(float));     // flagged fp32 L1
    float*    buf2     = (float*)   alloc((size_t)N_TOT * D * sizeof(float));     // flagged fp32 L2
    unsigned* ebfS     = (unsigned*)alloc((size_t)(N_TOT + 1) * 32 * sizeof(unsigned)); // scaled bf16 (+zero row); reused as bb2
    unsigned* bb1      = (unsigned*)alloc((size_t)(N_TOT + 1) * 32 * sizeof(unsigned));
    int*      nbr      = (int*)     alloc((size_t)NBUCK * BCAP * sizeof(int));    // padded item CSR (user idx)
    unsigned short* cols16 = (unsigned short*)alloc((size_t)E * sizeof(unsigned short));
    int*      user_ptr = (int*)     alloc((size_t)(N_USERS + 1) * sizeof(int));
    int*      ccur     = (int*)     alloc((size_t)NBUCK * sizeof(int));
    int*      item_beg = (int*)     alloc((size_t)N_ITEMS * sizeof(int));
    int*      item_end = (int*)     alloc((size_t)N_ITEMS * sizeof(int));
    float*    invrow   = (float*)   alloc((size_t)(N_TOT + 1) * sizeof(float));
    unsigned char* flags = (unsigned char*)alloc((size_t)N_TOT);
    int*      tmp      = (int*)buf1;   // alias: buf1 written only after preB

    // --- preprocessing (2 fused kernels) ---
    hipMemsetAsync(ccur, 0, (size_t)NBUCK * sizeof(int), stream);
    hipMemsetAsync(flags, 0, (size_t)N_TOT, stream);
    const int scatB = (E + 256 * SCAT_K - 1) / (256 * SCAT_K);
    preA_kernel<<<CONVU_B + FLAG_B + scatB, 256, 0, stream>>>(
        embeds, rows, cols, user_ptr, ebfS, invrow, users, pos, neg, flags,
        ccur, tmp, cols16, E, B);
    preB_kernel<<<NBUCK + 1, 256, 0, stream>>>(
        tmp, ccur, embeds, item_beg, item_end, nbr, ebfS, bb1, invrow);

    // --- layers 1,2: all rows (scaled bf16 out + flagged fp32 out) ---
    const int blocks = (N_TOT + 3) / 4;
    agg_kernel<<<blocks, 256, 0, stream>>>(ebfS, buf1, bb1, invrow, flags, user_ptr,
                                           cols16, item_beg, item_end, nbr);
    agg_kernel<<<blocks, 256, 0, stream>>>(bb1, buf2, ebfS, invrow, flags, user_ptr,
                                           cols16, item_beg, item_end, nbr);  // bb2 = ebfS

    // --- layer 3 + epilogue fused: only the 3*B output slots ---
    agg3_fused_kernel<<<(3 * B + 3) / 4, 256, 0, stream>>>(
        ebfS, embeds, buf1, buf2, invrow, users, pos, neg,
        user_ptr, cols16, item_beg, item_end, nbr, (float*)d_out, B);
}